// Round 10
// baseline (125.477 us; speedup 1.0000x reference)
//
#include <hip/hip_runtime.h>
#include <hip/hip_bf16.h>

#define EPS 0.1f
#define KSEL 16
#define KD 256
// MEASUREMENT SCAFFOLD (round 10): repeat both kernels' bodies writing
// identical outputs (deterministic, correct) to surface BOTH in rocprof
// top-5 above the 58-62us harness poison-fills. Remove next round.
#define REPS_G 10
#define REPS_S 3
#define SINK_ITERS 6   // was 12; contraction ~3e-3/iter after first jump

typedef __attribute__((ext_vector_type(4))) float f32x4;
typedef __attribute__((ext_vector_type(8))) short s16x8;
typedef __attribute__((ext_vector_type(4))) short s16x4;

__device__ inline s16x4 cvt4(f32x4 a) {
    s16x4 p;
    p[0] = __builtin_bit_cast(short, __float2bfloat16(a[0]));
    p[1] = __builtin_bit_cast(short, __float2bfloat16(a[1]));
    p[2] = __builtin_bit_cast(short, __float2bfloat16(a[2]));
    p[3] = __builtin_bit_cast(short, __float2bfloat16(a[3]));
    return p;
}

// R8 gemm, unchanged except REPS_G wrapper. Tile 128x64, BK=64, 8 waves,
// depth-2 register prefetch + double-buffered swizzled LDS, dist-only stores.
struct PF { f32x4 a[4]; f32x4 b[2]; };

__global__ __launch_bounds__(512, 4) void gemm_kernel(
    const float* __restrict__ Q, const float* __restrict__ Nb,
    float* __restrict__ dist,
    float* __restrict__ bmax, int Nn)
{
    __shared__ __align__(16) char As[2][128 * 128];
    __shared__ __align__(16) char Bs[2][64 * 128];
    __shared__ float wmax[8];

    const int t = threadIdx.x;
    const int lane = t & 63;
    const int wave = t >> 6;
    const int wr = wave >> 1;
    const int wc = wave & 1;
    const int brow = blockIdx.y * 128;
    const int bcol = blockIdx.x * 64;

    f32x4 acc[2][2];
    PF R0, R1;

    const int ra0 = t >> 3, pa0 = t & 7;
    const int ra1 = (512 + t) >> 3, pa1 = t & 7;
    const int rb  = t >> 3, pb = t & 7;

    auto issue = [&](PF& R, int kt) {
        const float* qa0 = &Q[(size_t)(brow + ra0) * KD + kt * 64 + pa0 * 8];
        R.a[0] = *reinterpret_cast<const f32x4*>(qa0);
        R.a[1] = *reinterpret_cast<const f32x4*>(qa0 + 4);
        const float* qa1 = &Q[(size_t)(brow + ra1) * KD + kt * 64 + pa1 * 8];
        R.a[2] = *reinterpret_cast<const f32x4*>(qa1);
        R.a[3] = *reinterpret_cast<const f32x4*>(qa1 + 4);
        const float* qb = &Nb[(size_t)(bcol + rb) * KD + kt * 64 + pb * 8];
        R.b[0] = *reinterpret_cast<const f32x4*>(qb);
        R.b[1] = *reinterpret_cast<const f32x4*>(qb + 4);
    };
    auto commit = [&](PF& R, int buf) {
        s16x8 v;
        s16x4 lo = cvt4(R.a[0]), hi = cvt4(R.a[1]);
        #pragma unroll
        for (int j = 0; j < 4; ++j) { v[j] = lo[j]; v[4 + j] = hi[j]; }
        *reinterpret_cast<s16x8*>(&As[buf][ra0 * 128 + ((pa0 * 16) ^ ((ra0 & 7) << 4))]) = v;
        lo = cvt4(R.a[2]); hi = cvt4(R.a[3]);
        #pragma unroll
        for (int j = 0; j < 4; ++j) { v[j] = lo[j]; v[4 + j] = hi[j]; }
        *reinterpret_cast<s16x8*>(&As[buf][ra1 * 128 + ((pa1 * 16) ^ ((ra1 & 7) << 4))]) = v;
        lo = cvt4(R.b[0]); hi = cvt4(R.b[1]);
        #pragma unroll
        for (int j = 0; j < 4; ++j) { v[j] = lo[j]; v[4 + j] = hi[j]; }
        *reinterpret_cast<s16x8*>(&Bs[buf][rb * 128 + ((pb * 16) ^ ((rb & 7) << 4))]) = v;
    };
    auto mfma_step = [&](int buf) {
        #pragma unroll
        for (int ks = 0; ks < 2; ++ks) {
            int kb = ks * 64 + ((lane >> 4) << 4);
            s16x8 af[2], bf[2];
            #pragma unroll
            for (int m = 0; m < 2; ++m) {
                int r = wr * 32 + m * 16 + (lane & 15);
                af[m] = *reinterpret_cast<const s16x8*>(
                    &As[buf][r * 128 + (kb ^ ((r & 7) << 4))]);
            }
            #pragma unroll
            for (int n = 0; n < 2; ++n) {
                int r = wc * 32 + n * 16 + (lane & 15);
                bf[n] = *reinterpret_cast<const s16x8*>(
                    &Bs[buf][r * 128 + (kb ^ ((r & 7) << 4))]);
            }
            #pragma unroll
            for (int m = 0; m < 2; ++m)
                #pragma unroll
                for (int n = 0; n < 2; ++n)
                    acc[m][n] = __builtin_amdgcn_mfma_f32_16x16x32_bf16(
                        af[m], bf[n], acc[m][n], 0, 0, 0);
        }
    };

    #pragma unroll 1
    for (int rep = 0; rep < REPS_G; ++rep) {
        const f32x4 z = {0.0f, 0.0f, 0.0f, 0.0f};
        #pragma unroll
        for (int m = 0; m < 2; ++m)
            #pragma unroll
            for (int n = 0; n < 2; ++n) acc[m][n] = z;

        issue(R0, 0);
        issue(R1, 1);
        commit(R0, 0);
        __syncthreads();

        issue(R0, 2);
        mfma_step(0);
        commit(R1, 1);
        __syncthreads();

        issue(R1, 3);
        mfma_step(1);
        commit(R0, 0);
        __syncthreads();

        mfma_step(0);
        commit(R1, 1);
        __syncthreads();

        mfma_step(1);
        __syncthreads();   // all waves done reading As[1]/Bs[1] before Ct write

        float* Ct = reinterpret_cast<float*>(&As[0][0]);   // [128][64] f32
        #pragma unroll
        for (int m = 0; m < 2; ++m)
            #pragma unroll
            for (int n = 0; n < 2; ++n)
                #pragma unroll
                for (int j = 0; j < 4; ++j) {
                    int row = wr * 32 + m * 16 + ((lane >> 4) << 2) + j;
                    int col = wc * 32 + n * 16 + (lane & 15);
                    Ct[row * 64 + col] = acc[m][n][j];
                }
        __syncthreads();

        float mx = 0.0f;
        #pragma unroll
        for (int it = 0; it < 4; ++it) {
            int r = wave * 16 + it * 4 + (lane >> 4);
            int c = (lane & 15) * 4;
            f32x4 v = *reinterpret_cast<f32x4*>(&Ct[r * 64 + c]);
            #pragma unroll
            for (int j = 0; j < 4; ++j) {
                float s = 1.0f - v[j];
                mx = fmaxf(mx, fmaxf(s * s, (s - 1.0f) * (s - 1.0f)));
            }
            size_t o = (size_t)(brow + r) * Nn + bcol + c;
            *reinterpret_cast<f32x4*>(&dist[o]) = v;
        }

        #pragma unroll
        for (int off = 32; off; off >>= 1) mx = fmaxf(mx, __shfl_xor(mx, off));
        if (lane == 0) wmax[wave] = mx;
        __syncthreads();
        if (t == 0) {
            float m2 = wmax[0];
            #pragma unroll
            for (int w = 1; w < 8; ++w) m2 = fmaxf(m2, wmax[w]);
            bmax[blockIdx.y * gridDim.x + blockIdx.x] = m2;
        }
    }
}

// R8 sinkhorn + REPS_S wrapper + SINK_ITERS=6.  Reads dist row, streams
// scor=1-dist (nontemporal), solves 2-col fixed point, streams masked out0.
__global__ __launch_bounds__(256) void sinkhorn_kernel(
    const float* __restrict__ dist, float* __restrict__ scor,
    float* __restrict__ out0,
    const float* __restrict__ bmax, int Nn, int nBmax)
{
    const int b = blockIdx.x;
    const int t = threadIdx.x;
    const int lane = t & 63;
    const int wave = t >> 6;
    __shared__ float sred[4];
    __shared__ float srho;
    __shared__ float sM;

    #pragma unroll 1
    for (int rep = 0; rep < REPS_S; ++rep) {
        float m = 0.0f;
        for (int i = t; i < nBmax; i += 256) m = fmaxf(m, bmax[i]);
        #pragma unroll
        for (int off = 32; off; off >>= 1) m = fmaxf(m, __shfl_xor(m, off));
        if (lane == 0) sred[wave] = m;
        __syncthreads();
        if (t == 0) sM = fmaxf(fmaxf(sred[0], sred[1]), fmaxf(sred[2], sred[3]));
        __syncthreads();
        const float Mmax = sM;

        const float invME = 1.0f / (Mmax * EPS);
        const float nuRatio = (float)(Nn - KSEL) / (float)KSEL;
        const float fn = (float)Nn;

        const float* drow = dist + (size_t)b * Nn;
        float* srow = scor + (size_t)b * Nn;
        float R[16];
        #pragma unroll
        for (int i = 0; i < 4; ++i) {
            f32x4 v4 = *reinterpret_cast<const f32x4*>(&drow[(i * 256 + t) * 4]);
            f32x4 s4;
            #pragma unroll
            for (int j = 0; j < 4; ++j) {
                float s = 1.0f - v4[j];
                s4[j] = s;
                R[i * 4 + j] = __expf((2.0f * s - 1.0f) * invME);
            }
            __builtin_nontemporal_store(s4,
                reinterpret_cast<f32x4*>(&srow[(i * 256 + t) * 4]));
        }

        float rho = 1.0f;
        for (int it = 0; it < SINK_ITERS; ++it) {
            float w = 0.0f;
            #pragma unroll
            for (int i = 0; i < 16; ++i)
                w += __builtin_amdgcn_rcpf(fmaf(rho, R[i], 1.0f));
            #pragma unroll
            for (int off = 32; off; off >>= 1) w += __shfl_xor(w, off);
            if (lane == 0) sred[wave] = w;
            __syncthreads();
            if (t == 0) {
                float W = sred[0] + sred[1] + sred[2] + sred[3];
                srho = rho * nuRatio * W / (fn - W);
            }
            __syncthreads();
            rho = srho;
        }

        float* orow = out0 + (size_t)b * Nn;
        #pragma unroll
        for (int i = 0; i < 4; ++i) {
            f32x4 v4;
            #pragma unroll
            for (int j = 0; j < 4; ++j) {
                float v = 1.0f / fmaf(rho, R[i * 4 + j], 1.0f);
                v4[j] = (v < 0.3f) ? 0.0f : v;
            }
            __builtin_nontemporal_store(v4,
                reinterpret_cast<f32x4*>(&orow[(i * 256 + t) * 4]));
        }
        __syncthreads();   // rep isolation: shared reuse ordered
    }
}

extern "C" void kernel_launch(void* const* d_in, const int* in_sizes, int n_in,
                              void* d_out, int out_size, void* d_ws, size_t ws_size,
                              hipStream_t stream) {
    const float* Q  = (const float*)d_in[0];
    const float* Nb = (const float*)d_in[1];
    const int Mrows = in_sizes[0] / KD;   // 2048
    const int Nn    = in_sizes[1] / KD;   // 4096

    float* out0 = (float*)d_out;                       // top_k_seq
    float* dist = out0 + (size_t)Mrows * Nn;           // distances
    float* scor = dist + (size_t)Mrows * Nn;           // scores
    float* bmax = (float*)d_ws;                        // per-block maxima

    dim3 g1(Nn / 64, Mrows / 128);                     // 64 x 16 = 1024 blocks
    gemm_kernel<<<g1, 512, 0, stream>>>(Q, Nb, dist, bmax, Nn);
    sinkhorn_kernel<<<Mrows, 256, 0, stream>>>(dist, scor, out0, bmax, Nn,
                                               g1.x * g1.y);
}

// Round 11
// 44.872 us; speedup vs baseline: 2.7963x; 2.7963x over previous
//
#include <hip/hip_runtime.h>
#include <hip/hip_bf16.h>

#define EPS 0.1f
#define KSEL 16
#define KD 256
#define SINK_ITERS 6   // contraction ~2e-4/iter; 6 is deep margin

typedef __attribute__((ext_vector_type(4))) float f32x4;
typedef __attribute__((ext_vector_type(8))) short s16x8;
typedef __attribute__((ext_vector_type(4))) short s16x4;

__device__ inline s16x4 cvt4(f32x4 a) {
    s16x4 p;
    p[0] = __builtin_bit_cast(short, __float2bfloat16(a[0]));
    p[1] = __builtin_bit_cast(short, __float2bfloat16(a[1]));
    p[2] = __builtin_bit_cast(short, __float2bfloat16(a[2]));
    p[3] = __builtin_bit_cast(short, __float2bfloat16(a[3]));
    return p;
}

// C[m][n] = sum_k Q[m][k]*Nb[n][k].  Tile 128x64, BK=64, 8 waves (4x2),
// depth-2 register prefetch + double-buffered swizzled LDS (R8 structure).
// Epilogue: C -> LDS (Ct, XOR-swizzled: kills the 262K/rep 4-way write
// conflicts measured in R9) -> f32x4 dist stores.  Per-block max -> bmax.
struct PF { f32x4 a[4]; f32x4 b[2]; };

__global__ __launch_bounds__(512, 4) void gemm_kernel(
    const float* __restrict__ Q, const float* __restrict__ Nb,
    float* __restrict__ dist,
    float* __restrict__ bmax, int Nn)
{
    __shared__ __align__(16) char As[2][128 * 128];
    __shared__ __align__(16) char Bs[2][64 * 128];
    __shared__ float wmax[8];

    const int t = threadIdx.x;
    const int lane = t & 63;
    const int wave = t >> 6;
    const int wr = wave >> 1;
    const int wc = wave & 1;
    const int brow = blockIdx.y * 128;
    const int bcol = blockIdx.x * 64;

    f32x4 acc[2][2] = {};
    PF R0, R1;

    const int ra0 = t >> 3, pa0 = t & 7;
    const int ra1 = (512 + t) >> 3, pa1 = t & 7;
    const int rb  = t >> 3, pb = t & 7;

    auto issue = [&](PF& R, int kt) {
        const float* qa0 = &Q[(size_t)(brow + ra0) * KD + kt * 64 + pa0 * 8];
        R.a[0] = *reinterpret_cast<const f32x4*>(qa0);
        R.a[1] = *reinterpret_cast<const f32x4*>(qa0 + 4);
        const float* qa1 = &Q[(size_t)(brow + ra1) * KD + kt * 64 + pa1 * 8];
        R.a[2] = *reinterpret_cast<const f32x4*>(qa1);
        R.a[3] = *reinterpret_cast<const f32x4*>(qa1 + 4);
        const float* qb = &Nb[(size_t)(bcol + rb) * KD + kt * 64 + pb * 8];
        R.b[0] = *reinterpret_cast<const f32x4*>(qb);
        R.b[1] = *reinterpret_cast<const f32x4*>(qb + 4);
    };
    auto commit = [&](PF& R, int buf) {
        s16x8 v;
        s16x4 lo = cvt4(R.a[0]), hi = cvt4(R.a[1]);
        #pragma unroll
        for (int j = 0; j < 4; ++j) { v[j] = lo[j]; v[4 + j] = hi[j]; }
        *reinterpret_cast<s16x8*>(&As[buf][ra0 * 128 + ((pa0 * 16) ^ ((ra0 & 7) << 4))]) = v;
        lo = cvt4(R.a[2]); hi = cvt4(R.a[3]);
        #pragma unroll
        for (int j = 0; j < 4; ++j) { v[j] = lo[j]; v[4 + j] = hi[j]; }
        *reinterpret_cast<s16x8*>(&As[buf][ra1 * 128 + ((pa1 * 16) ^ ((ra1 & 7) << 4))]) = v;
        lo = cvt4(R.b[0]); hi = cvt4(R.b[1]);
        #pragma unroll
        for (int j = 0; j < 4; ++j) { v[j] = lo[j]; v[4 + j] = hi[j]; }
        *reinterpret_cast<s16x8*>(&Bs[buf][rb * 128 + ((pb * 16) ^ ((rb & 7) << 4))]) = v;
    };
    auto mfma_step = [&](int buf) {
        #pragma unroll
        for (int ks = 0; ks < 2; ++ks) {
            int kb = ks * 64 + ((lane >> 4) << 4);
            s16x8 af[2], bf[2];
            #pragma unroll
            for (int m = 0; m < 2; ++m) {
                int r = wr * 32 + m * 16 + (lane & 15);
                af[m] = *reinterpret_cast<const s16x8*>(
                    &As[buf][r * 128 + (kb ^ ((r & 7) << 4))]);
            }
            #pragma unroll
            for (int n = 0; n < 2; ++n) {
                int r = wc * 32 + n * 16 + (lane & 15);
                bf[n] = *reinterpret_cast<const s16x8*>(
                    &Bs[buf][r * 128 + (kb ^ ((r & 7) << 4))]);
            }
            #pragma unroll
            for (int m = 0; m < 2; ++m)
                #pragma unroll
                for (int n = 0; n < 2; ++n)
                    acc[m][n] = __builtin_amdgcn_mfma_f32_16x16x32_bf16(
                        af[m], bf[n], acc[m][n], 0, 0, 0);
        }
    };

    issue(R0, 0);
    issue(R1, 1);
    commit(R0, 0);
    __syncthreads();

    issue(R0, 2);
    mfma_step(0);
    commit(R1, 1);
    __syncthreads();

    issue(R1, 3);
    mfma_step(1);
    commit(R0, 0);
    __syncthreads();

    mfma_step(0);
    commit(R1, 1);
    __syncthreads();

    mfma_step(1);
    __syncthreads();   // all waves done reading As[1]/Bs[1] before Ct write

    // Ct swizzle: c' = c ^ ((row>>2 & 3)<<4).  Store-instr rows differ by 4
    // -> 4 lane-groups land in 4 disjoint 16-bank blocks (2-way = free).
    // f32x4 readback unaffected (XOR touches only col bits 4-5).
    float* Ct = reinterpret_cast<float*>(&As[0][0]);   // [128][64] f32
    #pragma unroll
    for (int m = 0; m < 2; ++m)
        #pragma unroll
        for (int n = 0; n < 2; ++n)
            #pragma unroll
            for (int j = 0; j < 4; ++j) {
                int row = wr * 32 + m * 16 + ((lane >> 4) << 2) + j;
                int col = wc * 32 + n * 16 + (lane & 15);
                Ct[row * 64 + (col ^ (((row >> 2) & 3) << 4))] = acc[m][n][j];
            }
    __syncthreads();

    float mx = 0.0f;
    #pragma unroll
    for (int it = 0; it < 4; ++it) {
        int r = wave * 16 + it * 4 + (lane >> 4);
        int c = (lane & 15) * 4;
        f32x4 v = *reinterpret_cast<f32x4*>(&Ct[r * 64 + (c ^ (((r >> 2) & 3) << 4))]);
        #pragma unroll
        for (int j = 0; j < 4; ++j) {
            float s = 1.0f - v[j];
            mx = fmaxf(mx, fmaxf(s * s, (s - 1.0f) * (s - 1.0f)));
        }
        size_t o = (size_t)(brow + r) * Nn + bcol + c;
        *reinterpret_cast<f32x4*>(&dist[o]) = v;
    }

    #pragma unroll
    for (int off = 32; off; off >>= 1) mx = fmaxf(mx, __shfl_xor(mx, off));
    if (lane == 0) wmax[wave] = mx;
    __syncthreads();
    if (t == 0) {
        float m2 = wmax[0];
        #pragma unroll
        for (int w = 1; w < 8; ++w) m2 = fmaxf(m2, wmax[w]);
        bmax[blockIdx.y * gridDim.x + blockIdx.x] = m2;
    }
}

// ONE WAVE PER ROW (4 rows per 256-thread block): all reductions are 64-lane
// shfl butterflies -- zero __syncthreads, zero LDS.  Reads dist row, streams
// scor = 1 - dist (nontemporal), solves the 2-column Sinkhorn fixed point
// rho <- rho*(nu1/nu0)*W/(n-W), W = sum 1/(1+rho*R_i), R_i = exp((2s-1)/(M*EPS)),
// then streams masked out0 = 1/(1+rho*R) (nontemporal).
__global__ __launch_bounds__(256) void sinkhorn_kernel(
    const float* __restrict__ dist, float* __restrict__ scor,
    float* __restrict__ out0,
    const float* __restrict__ bmax, int Nn, int nBmax)
{
    const int t = threadIdx.x;
    const int lane = t & 63;
    const int wave = t >> 6;
    const int row = blockIdx.x * 4 + wave;

    // global C.max: wave-local reduce over bmax (L2-resident)
    float m = 0.0f;
    for (int i = lane; i < nBmax; i += 64) m = fmaxf(m, bmax[i]);
    #pragma unroll
    for (int off = 32; off; off >>= 1) m = fmaxf(m, __shfl_xor(m, off));

    const float invME = 1.0f / (m * EPS);
    const float nuRatio = (float)(Nn - KSEL) / (float)KSEL;
    const float fn = (float)Nn;

    const float* drow = dist + (size_t)row * Nn;
    float* srow = scor + (size_t)row * Nn;
    float* orow = out0 + (size_t)row * Nn;

    // lane handles 16 f32x4 chunks at (i*64+lane)*4 : coalesced 1KB/instr
    float R[64];
    #pragma unroll
    for (int i = 0; i < 16; ++i) {
        const int idx = (i * 64 + lane) * 4;
        f32x4 v4 = *reinterpret_cast<const f32x4*>(&drow[idx]);
        f32x4 s4;
        #pragma unroll
        for (int j = 0; j < 4; ++j) {
            float s = 1.0f - v4[j];
            s4[j] = s;
            // (2s-1)*invME = fma(-2*invME, d, invME)
            R[i * 4 + j] = __expf(fmaf(-2.0f * invME, v4[j], invME));
        }
        __builtin_nontemporal_store(s4, reinterpret_cast<f32x4*>(&srow[idx]));
    }

    float rho = 1.0f;   // g0 = g1 = 0 initial condition
    #pragma unroll 1
    for (int it = 0; it < SINK_ITERS; ++it) {
        float w = 0.0f;
        #pragma unroll
        for (int i = 0; i < 64; ++i)
            w += __builtin_amdgcn_rcpf(fmaf(rho, R[i], 1.0f));
        #pragma unroll
        for (int off = 32; off; off >>= 1) w += __shfl_xor(w, off);
        rho = rho * nuRatio * w / (fn - w);   // uniform across lanes
    }

    #pragma unroll
    for (int i = 0; i < 16; ++i) {
        f32x4 v4;
        #pragma unroll
        for (int j = 0; j < 4; ++j) {
            float v = 1.0f / fmaf(rho, R[i * 4 + j], 1.0f);
            v4[j] = (v < 0.3f) ? 0.0f : v;
        }
        __builtin_nontemporal_store(v4,
            reinterpret_cast<f32x4*>(&orow[(i * 64 + lane) * 4]));
    }
}

extern "C" void kernel_launch(void* const* d_in, const int* in_sizes, int n_in,
                              void* d_out, int out_size, void* d_ws, size_t ws_size,
                              hipStream_t stream) {
    const float* Q  = (const float*)d_in[0];
    const float* Nb = (const float*)d_in[1];
    const int Mrows = in_sizes[0] / KD;   // 2048
    const int Nn    = in_sizes[1] / KD;   // 4096

    float* out0 = (float*)d_out;                       // top_k_seq
    float* dist = out0 + (size_t)Mrows * Nn;           // distances
    float* scor = dist + (size_t)Mrows * Nn;           // scores
    float* bmax = (float*)d_ws;                        // per-block maxima

    dim3 g1(Nn / 64, Mrows / 128);                     // 64 x 16 = 1024 blocks
    gemm_kernel<<<g1, 512, 0, stream>>>(Q, Nb, dist, bmax, Nn);
    sinkhorn_kernel<<<Mrows / 4, 256, 0, stream>>>(dist, scor, out0, bmax, Nn,
                                                   g1.x * g1.y);
}